// Round 1
// baseline (211.552 us; speedup 1.0000x reference)
//
#include <hip/hip_runtime.h>

// y[e, o] = sum_i weight[widx[e]][o][i] * values[iidx[e]][i]
// E = 1e6, D_IN = D_OUT = 16, fp32.
//
// Layout: 4 threads per connection. Thread sub-index j in [0,4) computes
// output rows 4j..4j+3. All global accesses are float4:
//  - weight: 4 lanes x 16 loads of 16B cover the 1KB matrix contiguously
//  - x: 4 loads of 16B, broadcast across the 4 lanes of the group (cache)
//  - store: one float4 per lane; a full wave stores 1KB contiguous

#define D 16

__global__ __launch_bounds__(256) void linear_gather_mv(
    const float* __restrict__ values,
    const float* __restrict__ weight,
    const int*   __restrict__ input_idx,
    const int*   __restrict__ weight_idx,
    float*       __restrict__ out,
    int E)
{
    int tid = blockIdx.x * blockDim.x + threadIdx.x;
    int e = tid >> 2;   // connection index
    int j = tid & 3;    // which 4-row slab of the output
    if (e >= E) return;

    int ii = input_idx[e];
    int wi = weight_idx[e];

    const float4* xp = (const float4*)(values + (long long)ii * D);
    float4 x0 = xp[0];
    float4 x1 = xp[1];
    float4 x2 = xp[2];
    float4 x3 = xp[3];

    // rows [4j, 4j+4) of W[wi]; each row is 16 floats = 4 float4
    const float4* wp = (const float4*)(weight + (long long)wi * (D * D) + j * (4 * D));

    float4 acc;
    float* accp = (float*)&acc;

    #pragma unroll
    for (int r = 0; r < 4; ++r) {
        float4 w0 = wp[r * 4 + 0];
        float4 w1 = wp[r * 4 + 1];
        float4 w2 = wp[r * 4 + 2];
        float4 w3 = wp[r * 4 + 3];
        float s = w0.x * x0.x + w0.y * x0.y + w0.z * x0.z + w0.w * x0.w
                + w1.x * x1.x + w1.y * x1.y + w1.z * x1.z + w1.w * x1.w
                + w2.x * x2.x + w2.y * x2.y + w2.z * x2.z + w2.w * x2.w
                + w3.x * x3.x + w3.y * x3.y + w3.z * x3.z + w3.w * x3.w;
        accp[r] = s;
    }

    ((float4*)out)[(long long)e * 4 + j] = acc;
}

extern "C" void kernel_launch(void* const* d_in, const int* in_sizes, int n_in,
                              void* d_out, int out_size, void* d_ws, size_t ws_size,
                              hipStream_t stream) {
    const float* values     = (const float*)d_in[0];
    const float* weight     = (const float*)d_in[1];
    const int*   input_idx  = (const int*)d_in[2];
    const int*   weight_idx = (const int*)d_in[3];
    float*       out        = (float*)d_out;

    int E = in_sizes[2];               // number of connections
    int total_threads = E * 4;         // 4 lanes per connection
    int block = 256;
    int grid = (total_threads + block - 1) / block;

    hipLaunchKernelGGL(linear_gather_mv, dim3(grid), dim3(block), 0, stream,
                       values, weight, input_idx, weight_idx, out, E);
}